// Round 13
// baseline (1461.233 us; speedup 1.0000x reference)
//
#include <hip/hip_runtime.h>
#include <math.h>

// TfLSTM: x[512,256,128] -> LSTM(100, relu) -> LSTM(128, relu, last) -> Dense(19) -> softmax
// Round 18: (a) proj K-tail fix -- K=100 ran 4 full 32-k chunks (22% wasted
// FMA); now K/32 full chunks + constexpr K%32 remainder. (b) rec1 = r11's
// 8-way k-split RETRIED with its two bugs fixed: one-time pin (r11's in-loop
// pin forced per-iter copies) and h stored as 8 padded 20-dword slices
// (kq*20%32 = {0,20,8,28,16,4,24,12}, zero bank conflict vs r11's 4-way/33.5M
// at kq*16). 64 weight VGPRs < the ~88 the allocator provably keeps ->
// no remat possible in principle. 16 waves at (4,4), 1 barrier/step.
// Fallback if VGPR<70 or rec1>=450: revert rec1 to r10 (454us known).
// CLOSED BRANCHES: LDS-weights rec1 (r15, bank+issue floor ~560); 200-reg
// weight sets (r5-r12, allocator evicts); proj lambda reg-staging (r13,
// scratch spill); rec2 barrier cut (r16, neutral).
//   ws layout (floats): zxbuf 209.7MB | h1seq 52.4MB | cbuf/hbuf/h2buf 0.26MB ea.

#define T_SEQ 256
#define BATCH 512
#define IN_DIM 128
#define H1 100
#define H2 128
#define NCLS 19

typedef float f4v __attribute__((ext_vector_type(4)));

__device__ __forceinline__ float sigmoidf_(float x) {
    return 1.0f / (1.0f + __expf(-x));
}
__device__ __forceinline__ float hsum4_(f4v v) {
    return (v.x + v.y) + (v.z + v.w);
}

#define REP4(M)  M(0) M(1) M(2) M(3)
#define REP7(M)  M(0) M(1) M(2) M(3) M(4) M(5) M(6)
#define REP8(M)  M(0) M(1) M(2) M(3) M(4) M(5) M(6) M(7)

// =================== projection GEMM (r17 + K-tail) ===================
template<int K, int N, bool SWAP>
__global__ __launch_bounds__(256, 4)
void proj_kernel(const float* __restrict__ A, const float* __restrict__ W,
                 const float* __restrict__ bias, float* __restrict__ out)
{
    constexpr int LDA = 132;  // As row stride
    constexpr int WCG = 260;  // Ws colgroup stride (32*8 + 4)
    constexpr int REM = K % 32;
    constexpr int KFULL = K - REM;
    __shared__ __align__(16) float As[32 * LDA];   // 16.9 KB
    __shared__ __align__(16) float Ws[16 * WCG];   // 16.6 KB
    const int tid = threadIdx.x;
    const int r0 = blockIdx.x * 128;
    const int c0 = blockIdx.y * 128;
    const int ty = tid >> 4, tx = tid & 15;

#define PACC(i) f4v accL##i = {0.f,0.f,0.f,0.f}; f4v accR##i = {0.f,0.f,0.f,0.f};
    REP8(PACC)
#undef PACC

#define PROJ_FMA_BODY \
    { \
        f4v b0v = *(const f4v*)&Ws[tx * WCG + k * 8]; \
        f4v b1v = *(const f4v*)&Ws[tx * WCG + k * 8 + 4]; \
        f4v av0 = *(const f4v*)&As[k * LDA + ty * 8]; \
        f4v av1 = *(const f4v*)&As[k * LDA + ty * 8 + 4]; \
        accL0 += av0.x * b0v; accR0 += av0.x * b1v; \
        accL1 += av0.y * b0v; accR1 += av0.y * b1v; \
        accL2 += av0.z * b0v; accR2 += av0.z * b1v; \
        accL3 += av0.w * b0v; accR3 += av0.w * b1v; \
        accL4 += av1.x * b0v; accR4 += av1.x * b1v; \
        accL5 += av1.y * b0v; accR5 += av1.y * b1v; \
        accL6 += av1.z * b0v; accR6 += av1.z * b1v; \
        accL7 += av1.w * b0v; accR7 += av1.w * b1v; \
    }

    for (int kk = 0; kk < KFULL; kk += 32) {
        __syncthreads();
        // stage A chunk transposed: As[k][row] (k always < K in full chunks)
#pragma unroll
        for (int i = 0; i < 4; ++i) {
            int idx = tid + i * 256;          // 1024 float4 slots: 128 rows x 8 kgroups
            int row = idx >> 3, kg = idx & 7;
            int k = kk + kg * 4;
            f4v v = *(const f4v*)&A[(size_t)(r0 + row) * K + k];
            As[(kg * 4 + 0) * LDA + row] = v.x;
            As[(kg * 4 + 1) * LDA + row] = v.y;
            As[(kg * 4 + 2) * LDA + row] = v.z;
            As[(kg * 4 + 3) * LDA + row] = v.w;
        }
        // stage W chunk: Ws[cg][k*8 + half*4]
#pragma unroll
        for (int i = 0; i < 4; ++i) {
            int idx = tid + i * 256;          // 1024 float4 slots: 32 k x 32 colquads
            int k = idx >> 5, q = idx & 31;
            int gk = kk + k, gc = c0 + q * 4;
            f4v v = {0.f, 0.f, 0.f, 0.f};
            if (gc < N) v = *(const f4v*)&W[(size_t)gk * N + gc];
            int cg = q >> 1, half = q & 1;
            *(f4v*)&Ws[cg * WCG + k * 8 + half * 4] = v;
        }
        __syncthreads();
#pragma unroll
        for (int k = 0; k < 32; ++k) PROJ_FMA_BODY
    }

    if constexpr (REM > 0) {
        __syncthreads();
#pragma unroll
        for (int i = 0; i < 4; ++i) {
            int idx = tid + i * 256;
            int row = idx >> 3, kg = idx & 7;
            int k = KFULL + kg * 4;
            f4v v = {0.f, 0.f, 0.f, 0.f};
            if (k < K) v = *(const f4v*)&A[(size_t)(r0 + row) * K + k];
            As[(kg * 4 + 0) * LDA + row] = v.x;
            As[(kg * 4 + 1) * LDA + row] = v.y;
            As[(kg * 4 + 2) * LDA + row] = v.z;
            As[(kg * 4 + 3) * LDA + row] = v.w;
        }
#pragma unroll
        for (int i = 0; i < 4; ++i) {
            int idx = tid + i * 256;
            int k = idx >> 5, q = idx & 31;
            int gk = KFULL + k, gc = c0 + q * 4;
            f4v v = {0.f, 0.f, 0.f, 0.f};
            if (gk < K && gc < N) v = *(const f4v*)&W[(size_t)gk * N + gc];
            int cg = q >> 1, half = q & 1;
            *(f4v*)&Ws[cg * WCG + k * 8 + half * 4] = v;
        }
        __syncthreads();
#pragma unroll
        for (int k = 0; k < REM; ++k) PROJ_FMA_BODY   // only the valid tail iters
    }
#undef PROJ_FMA_BODY

    // epilogue: + bias, guarded f4 stores
    const int cb = c0 + tx * 8;
    float b0 = (cb + 0 < N) ? bias[cb + 0] : 0.f;
    float b1 = (cb + 1 < N) ? bias[cb + 1] : 0.f;
    float b2 = (cb + 2 < N) ? bias[cb + 2] : 0.f;
    float b3 = (cb + 3 < N) ? bias[cb + 3] : 0.f;
    float b4 = (cb + 4 < N) ? bias[cb + 4] : 0.f;
    float b5 = (cb + 5 < N) ? bias[cb + 5] : 0.f;
    float b6 = (cb + 6 < N) ? bias[cb + 6] : 0.f;
    float b7 = (cb + 7 < N) ? bias[cb + 7] : 0.f;
    f4v bL = {b0, b1, b2, b3};
    f4v bR = {b4, b5, b6, b7};
#define PST(i) { \
        int r = r0 + ty * 8 + i; \
        size_t orow = SWAP ? ((size_t)(r & 255) * BATCH + (r >> 8)) : (size_t)r; \
        if (cb < N)     { f4v v = accL##i + bL; *(f4v*)&out[orow * N + cb] = v; } \
        if (cb + 4 < N) { f4v v = accR##i + bR; *(f4v*)&out[orow * N + cb + 4] = v; } }
    REP8(PST)
#undef PST
}

// unconditional clamped-row weight column load (branchless).
// Rows >= H1 read row H1-1 (garbage value) -- nullified because hsP pad = 0.
__device__ __forceinline__ f4v ldw_(const float* __restrict__ U1, int kb, int col) {
    int k0 = (kb + 0 < H1) ? kb + 0 : H1 - 1;
    int k1 = (kb + 1 < H1) ? kb + 1 : H1 - 1;
    int k2 = (kb + 2 < H1) ? kb + 2 : H1 - 1;
    int k3 = (kb + 3 < H1) ? kb + 3 : H1 - 1;
    f4v v;
    v.x = U1[(size_t)k0 * 400 + col];
    v.y = U1[(size_t)k1 * 400 + col];
    v.z = U1[(size_t)k2 * 400 + col];
    v.w = U1[(size_t)k3 * 400 + col];
    return v;
}

// =================== recurrence, layer 1 (8-way k-split, bank-fixed) ===================
// 1024 threads, tid = cl*8 + kq: cl = tid>>3 (0..127, active < 100), kq =
// tid&7 (16 k each = 4 f4v over K padded 128). Thread owns gate-quad cols
// {cl, 100+cl, 200+cl, 300+cl}. Weights 16 f4v = 64 VGPR (< the ~88 the
// allocator provably keeps), ONE-TIME pin. h state: 8 padded 20-dword
// slices -- read addr kq*20 -> banks {0,20,8,28,16,4,24,12}, conflict-free
// (r11's kq*16 was 4-way, 33.5M conflicts). k-reduce = 3x shfl_xor (1,2,4).
// Double-buffered hsP -> ONE barrier/step. (4,4): 16 waves, 4/SIMD.
__global__ __launch_bounds__(1024)
__attribute__((amdgpu_waves_per_eu(4, 4)))
void rec1_kernel(const float* __restrict__ zx,   // [T][B][400]
                 const float* __restrict__ U1,   // [100][400]
                 float* __restrict__ h1seq)      // [T][B][100]
{
    const int row = blockIdx.x;
    const int tid = threadIdx.x;
    const int cl = tid >> 3;      // 0..127 (active < 100)
    const int kq = tid & 7;       // k-eighth
    const int cc = (cl < H1) ? cl : 0;   // clamp; clamped lanes never store
    __shared__ __align__(16) float hsP[2][8][20];  // [buf][slice][16 + 4 pad]

    // one-time weight load: 16 f4v (4 gate-cols x 4 f4v of k)
#define R1W(j) \
    f4v w0_##j = ldw_(U1, kq * 16 + 4 * (j), cc); \
    f4v w1_##j = ldw_(U1, kq * 16 + 4 * (j), 100 + cc); \
    f4v w2_##j = ldw_(U1, kq * 16 + 4 * (j), 200 + cc); \
    f4v w3_##j = ldw_(U1, kq * 16 + 4 * (j), 300 + cc);
    REP4(R1W)
#undef R1W
    // ONE-TIME pin (r10 pattern; r11's in-loop pin forced per-iter copies)
#define R1P(j) asm volatile("" : "+v"(w0_##j), "+v"(w1_##j), "+v"(w2_##j), "+v"(w3_##j));
    REP4(R1P)
#undef R1P

    if (tid < 320) ((float*)hsP)[tid] = 0.0f;    // zero both buffers incl. pads
    const bool tail = (kq == 0) && (cl < H1);
    float cst = 0.0f;
    float zc0 = 0.f, zc1 = 0.f, zc2 = 0.f, zc3 = 0.f;
    if (tail) {
        const float* pz = zx + (size_t)row * 400 + cl;
        zc0 = pz[0]; zc1 = pz[100]; zc2 = pz[200]; zc3 = pz[300];
    }
    __syncthreads();

    for (int t = 0; t < T_SEQ; ++t) {
        // prefetch next step's zx (hides under the FMA phase)
        float zn0 = 0.f, zn1 = 0.f, zn2 = 0.f, zn3 = 0.f;
        if (tail) {
            int tn = (t + 1 < T_SEQ) ? t + 1 : t;
            const float* pz = zx + ((size_t)tn * BATCH + row) * 400 + cl;
            zn0 = pz[0]; zn1 = pz[100]; zn2 = pz[200]; zn3 = pz[300];
        }

        const float* hb = &hsP[t & 1][0][0];
        f4v s0 = {0.f, 0.f, 0.f, 0.f};
        f4v s1 = {0.f, 0.f, 0.f, 0.f};
        f4v s2 = {0.f, 0.f, 0.f, 0.f};
        f4v s3 = {0.f, 0.f, 0.f, 0.f};
#define R1F(j) { f4v hv = *(const f4v*)&hb[kq * 20 + 4 * (j)]; \
        s0 += hv * w0_##j; s1 += hv * w1_##j; s2 += hv * w2_##j; s3 += hv * w3_##j; }
        REP4(R1F)
#undef R1F
        float a0 = hsum4_(s0);
        float a1 = hsum4_(s1);
        float a2 = hsum4_(s2);
        float a3 = hsum4_(s3);
        // k-reduce across the 8 kq lanes (adjacent lanes, same wave)
        a0 += __shfl_xor(a0, 1, 64); a0 += __shfl_xor(a0, 2, 64); a0 += __shfl_xor(a0, 4, 64);
        a1 += __shfl_xor(a1, 1, 64); a1 += __shfl_xor(a1, 2, 64); a1 += __shfl_xor(a1, 4, 64);
        a2 += __shfl_xor(a2, 1, 64); a2 += __shfl_xor(a2, 2, 64); a2 += __shfl_xor(a2, 4, 64);
        a3 += __shfl_xor(a3, 1, 64); a3 += __shfl_xor(a3, 2, 64); a3 += __shfl_xor(a3, 4, 64);

        if (tail) {
            float iv = sigmoidf_(zc0 + a0);            // gate order i, f, g, o
            float fv = sigmoidf_(zc1 + a1);
            float gv = fmaxf(zc2 + a2, 0.0f);          // candidate: relu
            float ov = sigmoidf_(zc3 + a3);
            cst = fv * cst + iv * gv;                  // c = f*c + i*g
            float h = ov * fmaxf(cst, 0.0f);           // h = o*relu(c)
            hsP[(t + 1) & 1][cl >> 4][cl & 15] = h;    // write NEXT buffer
            h1seq[((size_t)t * BATCH + row) * H1 + cl] = h;
            zc0 = zn0; zc1 = zn1; zc2 = zn2; zc3 = zn3;
        }
        __syncthreads();
    }
}

// =================== recurrence, layer 2 (r16: 2 barriers/step) ===================
template<bool INIT, bool LAST>
__global__ __launch_bounds__(512)
__attribute__((amdgpu_waves_per_eu(2, 2)))
void rec2_chunk(const float* __restrict__ zx,    // [tlen][B][512] (bias included)
                const float* __restrict__ U2,    // [128][512]
                float* __restrict__ cbuf,        // [B][128]
                float* __restrict__ hbuf,        // [B][128]
                float* __restrict__ h2out,       // [B][128] (used when LAST)
                int tlen)
{
    const int row = blockIdx.x;
    const int tid = threadIdx.x;   // 0..511
    const int kq = tid >> 7;
    const int cl = tid & 127;
    __shared__ __align__(16) float hs[H2];
    __shared__ float zp[4 * 512];

#define R2_LD(j) \
    f4v w0_##j, w1_##j, w2_##j, w3_##j; { \
        const float* p = U2 + (size_t)(kq * 32 + 4 * j) * 512 + cl; \
        w0_##j = (f4v){p[0],   p[512],       p[1024],       p[1536]}; \
        w1_##j = (f4v){p[128], p[512 + 128], p[1024 + 128], p[1536 + 128]}; \
        w2_##j = (f4v){p[256], p[512 + 256], p[1024 + 256], p[1536 + 256]}; \
        w3_##j = (f4v){p[384], p[512 + 384], p[1024 + 384], p[1536 + 384]}; }
    REP8(R2_LD)
#undef R2_LD
    // pin weights (keeps the gather rooted)
#define R2P(j) asm volatile("" : "+v"(w0_##j), "+v"(w1_##j), "+v"(w2_##j), "+v"(w3_##j));
    REP8(R2P)
#undef R2P

    const bool upd = (tid < H2);
    float cst = 0.0f;
    if (upd) {
        if (INIT) {
            hs[tid] = 0.0f;
        } else {
            hs[tid] = hbuf[(size_t)row * H2 + tid];
            cst = cbuf[(size_t)row * H2 + tid];
        }
    }
    // updater threads own all 4 gate columns {tid, tid+128, tid+256, tid+384}
    float zc0 = 0.f, zc1 = 0.f, zc2 = 0.f, zc3 = 0.f;
    if (upd) {
        const float* pz = zx + (size_t)row * 512 + tid;
        zc0 = pz[0]; zc1 = pz[128]; zc2 = pz[256]; zc3 = pz[384];
    }
    __syncthreads();

    for (int t = 0; t < tlen; ++t) {
        // prefetch next step's zx (updater threads only)
        float zn0 = 0.f, zn1 = 0.f, zn2 = 0.f, zn3 = 0.f;
        if (upd) {
            int tn = (t + 1 < tlen) ? t + 1 : t;
            const float* pz = zx + ((size_t)tn * BATCH + row) * 512 + tid;
            zn0 = pz[0]; zn1 = pz[128]; zn2 = pz[256]; zn3 = pz[384];
        }

        f4v s0 = {0.f, 0.f, 0.f, 0.f};
        f4v s1 = {0.f, 0.f, 0.f, 0.f};
        f4v s2 = {0.f, 0.f, 0.f, 0.f};
        f4v s3 = {0.f, 0.f, 0.f, 0.f};
#define R2_FMA(j) { f4v hv = *(const f4v*)&hs[kq * 32 + 4 * j]; \
        s0 += hv * w0_##j; s1 += hv * w1_##j; s2 += hv * w2_##j; s3 += hv * w3_##j; }
        REP8(R2_FMA)
#undef R2_FMA
        zp[kq * 512 + cl]       = hsum4_(s0);
        zp[kq * 512 + cl + 128] = hsum4_(s1);
        zp[kq * 512 + cl + 256] = hsum4_(s2);
        zp[kq * 512 + cl + 384] = hsum4_(s3);
        __syncthreads();   // barrier 1: zp complete; hs FMA-reads also complete

        if (upd) {
            float z0 = zc0 + (zp[tid]        + zp[512 + tid])
                           + (zp[1024 + tid] + zp[1536 + tid]);
            float z1 = zc1 + (zp[tid + 128]  + zp[512 + tid + 128])
                           + (zp[1024 + tid + 128] + zp[1536 + tid + 128]);
            float z2 = zc2 + (zp[tid + 256]  + zp[512 + tid + 256])
                           + (zp[1024 + tid + 256] + zp[1536 + tid + 256]);
            float z3 = zc3 + (zp[tid + 384]  + zp[512 + tid + 384])
                           + (zp[1024 + tid + 384] + zp[1536 + tid + 384]);
            float iv = sigmoidf_(z0);            // gate order i, f, g, o
            float fv = sigmoidf_(z1);
            float gv = fmaxf(z2, 0.0f);          // candidate: relu
            float ov = sigmoidf_(z3);
            cst = fv * cst + iv * gv;            // c = f*c + i*g
            hs[tid] = ov * fmaxf(cst, 0.0f);     // h = o*relu(c)
            zc0 = zn0; zc1 = zn1; zc2 = zn2; zc3 = zn3;
        }
        __syncthreads();   // barrier 2: hs(t+1) visible to all
    }

    if (upd) {
        float h = hs[tid];
        cbuf[(size_t)row * H2 + tid] = cst;
        hbuf[(size_t)row * H2 + tid] = h;
        if (LAST) h2out[(size_t)row * H2 + tid] = h;
    }
}

// =================== dense + softmax ===================
__global__ __launch_bounds__(64, 1)
void dense_softmax_kernel(const float* __restrict__ h2, const float* __restrict__ Wd,
                          const float* __restrict__ bd, float* __restrict__ out)
{
    const int b = blockIdx.x;
    const int k = threadIdx.x;
    __shared__ __align__(16) float hsm[H2];
    if (k < H2 / 4) ((f4v*)hsm)[k] = ((const f4v*)(h2 + (size_t)b * H2))[k];
    __syncthreads();

    float logit = -1e30f;
    if (k < NCLS) {
        float acc = bd[k];
#pragma unroll
        for (int d = 0; d < H2; ++d) acc += hsm[d] * Wd[d * NCLS + k];
        logit = acc;
    }
    float m = logit;
#pragma unroll
    for (int off = 32; off >= 1; off >>= 1) m = fmaxf(m, __shfl_xor(m, off, 64));
    float e = (k < NCLS) ? __expf(logit - m) : 0.0f;
    float s = e;
#pragma unroll
    for (int off = 32; off >= 1; off >>= 1) s += __shfl_xor(s, off, 64);
    if (k < NCLS) out[(size_t)b * NCLS + k] = e / s;
}

// =================== fallback (round-1) kernels ===================
__global__ __launch_bounds__(448, 1)
void lstm1_fb(const float* __restrict__ x, const float* __restrict__ W1,
              const float* __restrict__ U1, const float* __restrict__ b1,
              float* __restrict__ h1out)
{
    const int b = blockIdx.x;
    const int k = threadIdx.x;
    __shared__ __align__(16) float xs[IN_DIM];
    __shared__ __align__(16) float hs[H1];
    __shared__ __align__(16) float zs[4 * H1];
    float w1r[IN_DIM];
    float u1r[H1];
    float bias = 0.0f;
    if (k < 4 * H1) {
        bias = b1[k];
#pragma unroll
        for (int d = 0; d < IN_DIM; ++d) w1r[d] = W1[d * (4 * H1) + k];
#pragma unroll
        for (int j = 0; j < H1; ++j) u1r[j] = U1[j * (4 * H1) + k];
    }
    if (k < H1) hs[k] = 0.0f;
    if (k < IN_DIM / 4)
        ((float4*)xs)[k] = ((const float4*)(x + ((size_t)b * T_SEQ) * IN_DIM))[k];
    float c = 0.0f;
    __syncthreads();
    for (int t = 0; t < T_SEQ; ++t) {
        if (k < 4 * H1) {
            float acc0 = bias, acc1 = 0.f, acc2 = 0.f, acc3 = 0.f;
#pragma unroll
            for (int q = 0; q < IN_DIM / 4; ++q) {
                float4 xv = ((const float4*)xs)[q];
                acc0 += xv.x * w1r[4 * q]; acc1 += xv.y * w1r[4 * q + 1];
                acc2 += xv.z * w1r[4 * q + 2]; acc3 += xv.w * w1r[4 * q + 3];
            }
#pragma unroll
            for (int q = 0; q < H1 / 4; ++q) {
                float4 hv = ((const float4*)hs)[q];
                acc0 += hv.x * u1r[4 * q]; acc1 += hv.y * u1r[4 * q + 1];
                acc2 += hv.z * u1r[4 * q + 2]; acc3 += hv.w * u1r[4 * q + 3];
            }
            float zv = (acc0 + acc1) + (acc2 + acc3);
            zs[k] = (k >= 2 * H1 && k < 3 * H1) ? fmaxf(zv, 0.0f) : sigmoidf_(zv);
        }
        __syncthreads();
        if (k < H1) {
            float i = zs[k], f = zs[k + H1], g = zs[k + 2 * H1], o = zs[k + 3 * H1];
            c = f * c + i * g;
            float h = o * fmaxf(c, 0.0f);
            hs[k] = h;
            h1out[((size_t)t * BATCH + b) * H1 + k] = h;
        }
        int tn = t + 1;
        if (tn < T_SEQ && k < IN_DIM / 4)
            ((float4*)xs)[k] = ((const float4*)(x + ((size_t)b * T_SEQ + tn) * IN_DIM))[k];
        __syncthreads();
    }
}

__global__ __launch_bounds__(512, 1)
void lstm2_fb(const float* __restrict__ h1in, const float* __restrict__ W2,
              const float* __restrict__ U2, const float* __restrict__ b2,
              float* __restrict__ h2out)
{
    const int b = blockIdx.x;
    const int k = threadIdx.x;
    __shared__ __align__(16) float ps[H1];
    __shared__ __align__(16) float hs[H2];
    __shared__ __align__(16) float zs[4 * H2];
    float w2r[H1];
    float u2r[H2];
    float bias = b2[k];
#pragma unroll
    for (int j = 0; j < H1; ++j) w2r[j] = W2[j * (4 * H2) + k];
#pragma unroll
    for (int j = 0; j < H2; ++j) u2r[j] = U2[j * (4 * H2) + k];
    if (k < H2) hs[k] = 0.0f;
    if (k < H1 / 4)
        ((float4*)ps)[k] = ((const float4*)(h1in + (size_t)b * H1))[k];
    float c = 0.0f;
    float hlast = 0.0f;
    __syncthreads();
    for (int t = 0; t < T_SEQ; ++t) {
        float acc0 = bias, acc1 = 0.f, acc2 = 0.f, acc3 = 0.f;
#pragma unroll
        for (int q = 0; q < H1 / 4; ++q) {
            float4 pv = ((const float4*)ps)[q];
            acc0 += pv.x * w2r[4 * q]; acc1 += pv.y * w2r[4 * q + 1];
            acc2 += pv.z * w2r[4 * q + 2]; acc3 += pv.w * w2r[4 * q + 3];
        }
#pragma unroll
        for (int q = 0; q < H2 / 4; ++q) {
            float4 hv = ((const float4*)hs)[q];
            acc0 += hv.x * u2r[4 * q]; acc1 += hv.y * u2r[4 * q + 1];
            acc2 += hv.z * u2r[4 * q + 2]; acc3 += hv.w * u2r[4 * q + 3];
        }
        float zv = (acc0 + acc1) + (acc2 + acc3);
        zs[k] = (k >= 2 * H2 && k < 3 * H2) ? fmaxf(zv, 0.0f) : sigmoidf_(zv);
        __syncthreads();
        if (k < H2) {
            float i = zs[k], f = zs[k + H2], g = zs[k + 2 * H2], o = zs[k + 3 * H2];
            c = f * c + i * g;
            hlast = o * fmaxf(c, 0.0f);
            hs[k] = hlast;
        }
        int tn = t + 1;
        if (tn < T_SEQ && k < H1 / 4)
            ((float4*)ps)[k] = ((const float4*)(h1in + ((size_t)tn * BATCH + b) * H1))[k];
        __syncthreads();
    }
    if (k < H2) h2out[(size_t)b * H2 + k] = hlast;
}

extern "C" void kernel_launch(void* const* d_in, const int* in_sizes, int n_in,
                              void* d_out, int out_size, void* d_ws, size_t ws_size,
                              hipStream_t stream) {
    const float* x  = (const float*)d_in[0];
    const float* W1 = (const float*)d_in[1];
    const float* U1 = (const float*)d_in[2];
    const float* b1 = (const float*)d_in[3];
    const float* W2 = (const float*)d_in[4];
    const float* U2 = (const float*)d_in[5];
    const float* b2 = (const float*)d_in[6];
    const float* Wd = (const float*)d_in[7];
    const float* bd = (const float*)d_in[8];
    float* out = (float*)d_out;

    const size_t zx_elems = (size_t)T_SEQ * BATCH * 400;   // 52428800
    const size_t h1_elems = (size_t)T_SEQ * BATCH * H1;    // 13107200
    const size_t st_elems = (size_t)BATCH * H2;            // 65536
    const size_t need = (zx_elems + h1_elems + 3 * st_elems) * sizeof(float);  // 262.93 MB

    if (ws_size >= need) {
        float* zxbuf = (float*)d_ws;
        float* h1buf = zxbuf + zx_elems;
        float* cbuf  = h1buf + h1_elems;
        float* hbuf  = cbuf + st_elems;
        float* h2buf = hbuf + st_elems;
        const int TC = T_SEQ / 2;   // 128-step chunks

        // zx1 = x @ W1 + b1 -> [T][B][400]
        hipLaunchKernelGGL((proj_kernel<IN_DIM, 4 * H1, true>), dim3(1024, 4), dim3(256), 0, stream,
                           x, W1, b1, zxbuf);
        hipLaunchKernelGGL(rec1_kernel, dim3(BATCH), dim3(1024), 0, stream,
                           zxbuf, U1, h1buf);
        // ---- layer 2, chunk A (t = 0..127): zx2 chunk overwrites zx1 region ----
        hipLaunchKernelGGL((proj_kernel<H1, 4 * H2, false>), dim3(512, 4), dim3(256), 0, stream,
                           h1buf, W2, b2, zxbuf);
        hipLaunchKernelGGL((rec2_chunk<true, false>), dim3(BATCH), dim3(512), 0, stream,
                           zxbuf, U2, cbuf, hbuf, h2buf, TC);
        // ---- layer 2, chunk B (t = 128..255) ----
        hipLaunchKernelGGL((proj_kernel<H1, 4 * H2, false>), dim3(512, 4), dim3(256), 0, stream,
                           h1buf + (size_t)TC * BATCH * H1, W2, b2, zxbuf);
        hipLaunchKernelGGL((rec2_chunk<false, true>), dim3(BATCH), dim3(512), 0, stream,
                           zxbuf, U2, cbuf, hbuf, h2buf, TC);

        hipLaunchKernelGGL(dense_softmax_kernel, dim3(BATCH), dim3(64), 0, stream,
                           h2buf, Wd, bd, out);
    } else {
        // fallback: round-1 fused kernels (needs ~52.7 MB)
        float* h1buf = (float*)d_ws;
        float* h2buf = h1buf + h1_elems;
        hipLaunchKernelGGL(lstm1_fb, dim3(BATCH), dim3(448), 0, stream, x, W1, U1, b1, h1buf);
        hipLaunchKernelGGL(lstm2_fb, dim3(BATCH), dim3(512), 0, stream, h1buf, W2, U2, b2, h2buf);
        hipLaunchKernelGGL(dense_softmax_kernel, dim3(BATCH), dim3(64), 0, stream, h2buf, Wd, bd, out);
    }
}

// Round 14
// 1346.957 us; speedup vs baseline: 1.0848x; 1.0848x over previous
//
#include <hip/hip_runtime.h>
#include <math.h>

// TfLSTM: x[512,256,128] -> LSTM(100, relu) -> LSTM(128, relu, last) -> Dense(19) -> softmax
// Round 19: rec1 reverted to r10 (454us best-of-13) with ONE attribute change:
// waves_per_eu (2,2) -> (2,4). min=2 keeps the identical 256-reg allocator
// budget (codegen unchanged, VGPR_Count must stay 88); max=4 only LIFTS the
// residency cap so the HW can co-schedule a 2nd 8-wave block per CU if the
// true unified (arch+AGPR) allocation <= 128 regs/wave -> 512 blocks in ONE
// round instead of two. Zero-downside discriminator: no-fire = unified regs
// >128 = occupancy genuinely reg-capped (family roofline). Same (2,4) on rec2.
// r18 post-mortem: 8-way k-split CLOSED (64-reg weights still AGPR-split,
// VGPR=56, accvgpr reads + 12 shfl > occupancy gain, 642us). proj K-tail
// kept (neutral-measured, strictly less FMA work).
// CLOSED BRANCHES: LDS-weights rec1 (r15); 8-way k-split rec1 (r11/r18);
// 200-reg weight sets (r5-r12); proj lambda reg-staging (r13); rec2 barrier
// cut beyond 2 (r16 neutral).
//   ws layout (floats): zxbuf 209.7MB | h1seq 52.4MB | cbuf/hbuf/h2buf 0.26MB ea.

#define T_SEQ 256
#define BATCH 512
#define IN_DIM 128
#define H1 100
#define H2 128
#define NCLS 19

typedef float f4v __attribute__((ext_vector_type(4)));

__device__ __forceinline__ float sigmoidf_(float x) {
    return 1.0f / (1.0f + __expf(-x));
}
__device__ __forceinline__ float hsum4_(f4v v) {
    return (v.x + v.y) + (v.z + v.w);
}

#define REP4(M)  M(0) M(1) M(2) M(3)
#define REP7(M)  M(0) M(1) M(2) M(3) M(4) M(5) M(6)
#define REP8(M)  M(0) M(1) M(2) M(3) M(4) M(5) M(6) M(7)

// =================== projection GEMM (r18: (256,4) + K-tail) ===================
template<int K, int N, bool SWAP>
__global__ __launch_bounds__(256, 4)
void proj_kernel(const float* __restrict__ A, const float* __restrict__ W,
                 const float* __restrict__ bias, float* __restrict__ out)
{
    constexpr int LDA = 132;  // As row stride
    constexpr int WCG = 260;  // Ws colgroup stride (32*8 + 4)
    constexpr int REM = K % 32;
    constexpr int KFULL = K - REM;
    __shared__ __align__(16) float As[32 * LDA];   // 16.9 KB
    __shared__ __align__(16) float Ws[16 * WCG];   // 16.6 KB
    const int tid = threadIdx.x;
    const int r0 = blockIdx.x * 128;
    const int c0 = blockIdx.y * 128;
    const int ty = tid >> 4, tx = tid & 15;

#define PACC(i) f4v accL##i = {0.f,0.f,0.f,0.f}; f4v accR##i = {0.f,0.f,0.f,0.f};
    REP8(PACC)
#undef PACC

#define PROJ_FMA_BODY \
    { \
        f4v b0v = *(const f4v*)&Ws[tx * WCG + k * 8]; \
        f4v b1v = *(const f4v*)&Ws[tx * WCG + k * 8 + 4]; \
        f4v av0 = *(const f4v*)&As[k * LDA + ty * 8]; \
        f4v av1 = *(const f4v*)&As[k * LDA + ty * 8 + 4]; \
        accL0 += av0.x * b0v; accR0 += av0.x * b1v; \
        accL1 += av0.y * b0v; accR1 += av0.y * b1v; \
        accL2 += av0.z * b0v; accR2 += av0.z * b1v; \
        accL3 += av0.w * b0v; accR3 += av0.w * b1v; \
        accL4 += av1.x * b0v; accR4 += av1.x * b1v; \
        accL5 += av1.y * b0v; accR5 += av1.y * b1v; \
        accL6 += av1.z * b0v; accR6 += av1.z * b1v; \
        accL7 += av1.w * b0v; accR7 += av1.w * b1v; \
    }

    for (int kk = 0; kk < KFULL; kk += 32) {
        __syncthreads();
        // stage A chunk transposed: As[k][row] (k always < K in full chunks)
#pragma unroll
        for (int i = 0; i < 4; ++i) {
            int idx = tid + i * 256;          // 1024 float4 slots: 128 rows x 8 kgroups
            int row = idx >> 3, kg = idx & 7;
            int k = kk + kg * 4;
            f4v v = *(const f4v*)&A[(size_t)(r0 + row) * K + k];
            As[(kg * 4 + 0) * LDA + row] = v.x;
            As[(kg * 4 + 1) * LDA + row] = v.y;
            As[(kg * 4 + 2) * LDA + row] = v.z;
            As[(kg * 4 + 3) * LDA + row] = v.w;
        }
        // stage W chunk: Ws[cg][k*8 + half*4]
#pragma unroll
        for (int i = 0; i < 4; ++i) {
            int idx = tid + i * 256;          // 1024 float4 slots: 32 k x 32 colquads
            int k = idx >> 5, q = idx & 31;
            int gk = kk + k, gc = c0 + q * 4;
            f4v v = {0.f, 0.f, 0.f, 0.f};
            if (gc < N) v = *(const f4v*)&W[(size_t)gk * N + gc];
            int cg = q >> 1, half = q & 1;
            *(f4v*)&Ws[cg * WCG + k * 8 + half * 4] = v;
        }
        __syncthreads();
#pragma unroll
        for (int k = 0; k < 32; ++k) PROJ_FMA_BODY
    }

    if constexpr (REM > 0) {
        __syncthreads();
#pragma unroll
        for (int i = 0; i < 4; ++i) {
            int idx = tid + i * 256;
            int row = idx >> 3, kg = idx & 7;
            int k = KFULL + kg * 4;
            f4v v = {0.f, 0.f, 0.f, 0.f};
            if (k < K) v = *(const f4v*)&A[(size_t)(r0 + row) * K + k];
            As[(kg * 4 + 0) * LDA + row] = v.x;
            As[(kg * 4 + 1) * LDA + row] = v.y;
            As[(kg * 4 + 2) * LDA + row] = v.z;
            As[(kg * 4 + 3) * LDA + row] = v.w;
        }
#pragma unroll
        for (int i = 0; i < 4; ++i) {
            int idx = tid + i * 256;
            int k = idx >> 5, q = idx & 31;
            int gk = KFULL + k, gc = c0 + q * 4;
            f4v v = {0.f, 0.f, 0.f, 0.f};
            if (gk < K && gc < N) v = *(const f4v*)&W[(size_t)gk * N + gc];
            int cg = q >> 1, half = q & 1;
            *(f4v*)&Ws[cg * WCG + k * 8 + half * 4] = v;
        }
        __syncthreads();
#pragma unroll
        for (int k = 0; k < REM; ++k) PROJ_FMA_BODY   // only the valid tail iters
    }
#undef PROJ_FMA_BODY

    // epilogue: + bias, guarded f4 stores
    const int cb = c0 + tx * 8;
    float b0 = (cb + 0 < N) ? bias[cb + 0] : 0.f;
    float b1 = (cb + 1 < N) ? bias[cb + 1] : 0.f;
    float b2 = (cb + 2 < N) ? bias[cb + 2] : 0.f;
    float b3 = (cb + 3 < N) ? bias[cb + 3] : 0.f;
    float b4 = (cb + 4 < N) ? bias[cb + 4] : 0.f;
    float b5 = (cb + 5 < N) ? bias[cb + 5] : 0.f;
    float b6 = (cb + 6 < N) ? bias[cb + 6] : 0.f;
    float b7 = (cb + 7 < N) ? bias[cb + 7] : 0.f;
    f4v bL = {b0, b1, b2, b3};
    f4v bR = {b4, b5, b6, b7};
#define PST(i) { \
        int r = r0 + ty * 8 + i; \
        size_t orow = SWAP ? ((size_t)(r & 255) * BATCH + (r >> 8)) : (size_t)r; \
        if (cb < N)     { f4v v = accL##i + bL; *(f4v*)&out[orow * N + cb] = v; } \
        if (cb + 4 < N) { f4v v = accR##i + bR; *(f4v*)&out[orow * N + cb + 4] = v; } }
    REP8(PST)
#undef PST
}

// unconditional clamped-row weight column load (branchless).
// Rows >= H1 read row H1-1 (garbage value) -- nullified because hsP pad = 0.
__device__ __forceinline__ f4v ldw_(const float* __restrict__ U1, int kb, int col) {
    int k0 = (kb + 0 < H1) ? kb + 0 : H1 - 1;
    int k1 = (kb + 1 < H1) ? kb + 1 : H1 - 1;
    int k2 = (kb + 2 < H1) ? kb + 2 : H1 - 1;
    int k3 = (kb + 3 < H1) ? kb + 3 : H1 - 1;
    f4v v;
    v.x = U1[(size_t)k0 * 400 + col];
    v.y = U1[(size_t)k1 * 400 + col];
    v.z = U1[(size_t)k2 * 400 + col];
    v.w = U1[(size_t)k3 * 400 + col];
    return v;
}

// =================== recurrence, layer 1 (r10 structure, residency cap lifted) ===================
// 512 threads, lane map tid = cl*4 + kq: cl = tid>>2 (0..127, active < 100),
// kq = tid&3 (k-quarter over padded K=112, 28 k each = 7 f4v). Thread owns the
// GATE QUAD cols {cl, 100+cl, 200+cl, 300+cl}; k-reduce = 2x shfl_xor in-wave.
// Weights: 28 f4v, one-time load + one-time asm pin (r10; fastest of 13).
// waves_per_eu(2,4): min=2 keeps the SAME 256-reg budget (codegen identical
// to r10, VGPR_Count=88); max=4 lifts the residency cap so a 2nd block/CU
// can co-schedule if unified (arch+AGPR) allocation <= 128/wave -> one round.
__global__ __launch_bounds__(512)
__attribute__((amdgpu_waves_per_eu(2, 4)))
void rec1_kernel(const float* __restrict__ zx,   // [T][B][400]
                 const float* __restrict__ U1,   // [100][400]
                 float* __restrict__ h1seq)      // [T][B][100]
{
    const int row = blockIdx.x;
    const int tid = threadIdx.x;
    const int cl = tid >> 2;      // column 0..127 (active < 100)
    const int kq = tid & 3;       // k-quarter
    const int cc = (cl < H1) ? cl : 0;   // clamp; clamped lanes never store
    __shared__ __align__(16) float hsP[2][112];  // double-buffered h state (pad 100..111 = 0)

    // one-time weight load: 28 f4v SSA values (4 gate-cols x 7 f4v of k)
#define R1W(j) \
    f4v w0_##j = ldw_(U1, kq * 28 + 4 * (j), cc); \
    f4v w1_##j = ldw_(U1, kq * 28 + 4 * (j), 100 + cc); \
    f4v w2_##j = ldw_(U1, kq * 28 + 4 * (j), 200 + cc); \
    f4v w3_##j = ldw_(U1, kq * 28 + 4 * (j), 300 + cc);
    REP7(R1W)
#undef R1W
    // one-time pin (r10): asm outputs cannot be rematerialized
#define R1P(j) asm volatile("" : "+v"(w0_##j), "+v"(w1_##j), "+v"(w2_##j), "+v"(w3_##j));
    REP7(R1P)
#undef R1P

    if (tid < 112) { hsP[0][tid] = 0.0f; hsP[1][tid] = 0.0f; }
    const bool tail = (kq == 0) && (cl < H1);
    float cst = 0.0f;
    float zc0 = 0.f, zc1 = 0.f, zc2 = 0.f, zc3 = 0.f;
    if (tail) {
        const float* pz = zx + (size_t)row * 400 + cl;
        zc0 = pz[0]; zc1 = pz[100]; zc2 = pz[200]; zc3 = pz[300];
    }
    __syncthreads();

    for (int t = 0; t < T_SEQ; ++t) {
        // prefetch next step's zx FIRST -- latency hides under the FMA phase
        float zn0 = 0.f, zn1 = 0.f, zn2 = 0.f, zn3 = 0.f;
        if (tail) {
            int tn = (t + 1 < T_SEQ) ? t + 1 : t;
            const float* pz = zx + ((size_t)tn * BATCH + row) * 400 + cl;
            zn0 = pz[0]; zn1 = pz[100]; zn2 = pz[200]; zn3 = pz[300];
        }

        const float* hb = hsP[t & 1];
        f4v s0 = {0.f, 0.f, 0.f, 0.f};
        f4v s1 = {0.f, 0.f, 0.f, 0.f};
        f4v s2 = {0.f, 0.f, 0.f, 0.f};
        f4v s3 = {0.f, 0.f, 0.f, 0.f};
#define R1F(j) { f4v hv = *(const f4v*)&hb[kq * 28 + 4 * (j)]; \
        s0 += hv * w0_##j; s1 += hv * w1_##j; s2 += hv * w2_##j; s3 += hv * w3_##j; }
        REP7(R1F)
#undef R1F
        float a0 = hsum4_(s0);
        float a1 = hsum4_(s1);
        float a2 = hsum4_(s2);
        float a3 = hsum4_(s3);
        // k-reduce across the 4 kq lanes (adjacent lanes, same wave)
        a0 += __shfl_xor(a0, 1, 64); a0 += __shfl_xor(a0, 2, 64);
        a1 += __shfl_xor(a1, 1, 64); a1 += __shfl_xor(a1, 2, 64);
        a2 += __shfl_xor(a2, 1, 64); a2 += __shfl_xor(a2, 2, 64);
        a3 += __shfl_xor(a3, 1, 64); a3 += __shfl_xor(a3, 2, 64);

        if (tail) {
            float z0 = zc0 + a0;                 // gate order i, f, g, o
            float z1 = zc1 + a1;
            float z2 = zc2 + a2;
            float z3 = zc3 + a3;
            float iv = sigmoidf_(z0);
            float fv = sigmoidf_(z1);
            float gv = fmaxf(z2, 0.0f);          // g: relu
            float ov = sigmoidf_(z3);
            cst = fv * cst + iv * gv;            // c = f*c + i*g
            float h = ov * fmaxf(cst, 0.0f);     // h = o*relu(c)
            hsP[(t + 1) & 1][cl] = h;            // write NEXT buffer: no WAR race
            h1seq[((size_t)t * BATCH + row) * H1 + cl] = h;
            zc0 = zn0; zc1 = zn1; zc2 = zn2; zc3 = zn3;
        }
        __syncthreads();
    }
}

// =================== recurrence, layer 2 (r16, residency cap lifted) ===================
template<bool INIT, bool LAST>
__global__ __launch_bounds__(512)
__attribute__((amdgpu_waves_per_eu(2, 4)))
void rec2_chunk(const float* __restrict__ zx,    // [tlen][B][512] (bias included)
                const float* __restrict__ U2,    // [128][512]
                float* __restrict__ cbuf,        // [B][128]
                float* __restrict__ hbuf,        // [B][128]
                float* __restrict__ h2out,       // [B][128] (used when LAST)
                int tlen)
{
    const int row = blockIdx.x;
    const int tid = threadIdx.x;   // 0..511
    const int kq = tid >> 7;
    const int cl = tid & 127;
    __shared__ __align__(16) float hs[H2];
    __shared__ float zp[4 * 512];

#define R2_LD(j) \
    f4v w0_##j, w1_##j, w2_##j, w3_##j; { \
        const float* p = U2 + (size_t)(kq * 32 + 4 * j) * 512 + cl; \
        w0_##j = (f4v){p[0],   p[512],       p[1024],       p[1536]}; \
        w1_##j = (f4v){p[128], p[512 + 128], p[1024 + 128], p[1536 + 128]}; \
        w2_##j = (f4v){p[256], p[512 + 256], p[1024 + 256], p[1536 + 256]}; \
        w3_##j = (f4v){p[384], p[512 + 384], p[1024 + 384], p[1536 + 384]}; }
    REP8(R2_LD)
#undef R2_LD
    // pin weights (keeps the gather rooted)
#define R2P(j) asm volatile("" : "+v"(w0_##j), "+v"(w1_##j), "+v"(w2_##j), "+v"(w3_##j));
    REP8(R2P)
#undef R2P

    const bool upd = (tid < H2);
    float cst = 0.0f;
    if (upd) {
        if (INIT) {
            hs[tid] = 0.0f;
        } else {
            hs[tid] = hbuf[(size_t)row * H2 + tid];
            cst = cbuf[(size_t)row * H2 + tid];
        }
    }
    // updater threads own all 4 gate columns {tid, tid+128, tid+256, tid+384}
    float zc0 = 0.f, zc1 = 0.f, zc2 = 0.f, zc3 = 0.f;
    if (upd) {
        const float* pz = zx + (size_t)row * 512 + tid;
        zc0 = pz[0]; zc1 = pz[128]; zc2 = pz[256]; zc3 = pz[384];
    }
    __syncthreads();

    for (int t = 0; t < tlen; ++t) {
        // prefetch next step's zx (updater threads only)
        float zn0 = 0.f, zn1 = 0.f, zn2 = 0.f, zn3 = 0.f;
        if (upd) {
            int tn = (t + 1 < tlen) ? t + 1 : t;
            const float* pz = zx + ((size_t)tn * BATCH + row) * 512 + tid;
            zn0 = pz[0]; zn1 = pz[128]; zn2 = pz[256]; zn3 = pz[384];
        }

        f4v s0 = {0.f, 0.f, 0.f, 0.f};
        f4v s1 = {0.f, 0.f, 0.f, 0.f};
        f4v s2 = {0.f, 0.f, 0.f, 0.f};
        f4v s3 = {0.f, 0.f, 0.f, 0.f};
#define R2_FMA(j) { f4v hv = *(const f4v*)&hs[kq * 32 + 4 * j]; \
        s0 += hv * w0_##j; s1 += hv * w1_##j; s2 += hv * w2_##j; s3 += hv * w3_##j; }
        REP8(R2_FMA)
#undef R2_FMA
        zp[kq * 512 + cl]       = hsum4_(s0);
        zp[kq * 512 + cl + 128] = hsum4_(s1);
        zp[kq * 512 + cl + 256] = hsum4_(s2);
        zp[kq * 512 + cl + 384] = hsum4_(s3);
        __syncthreads();   // barrier 1: zp complete; hs FMA-reads also complete

        if (upd) {
            float z0 = zc0 + (zp[tid]        + zp[512 + tid])
                           + (zp[1024 + tid] + zp[1536 + tid]);
            float z1 = zc1 + (zp[tid + 128]  + zp[512 + tid + 128])
                           + (zp[1024 + tid + 128] + zp[1536 + tid + 128]);
            float z2 = zc2 + (zp[tid + 256]  + zp[512 + tid + 256])
                           + (zp[1024 + tid + 256] + zp[1536 + tid + 256]);
            float z3 = zc3 + (zp[tid + 384]  + zp[512 + tid + 384])
                           + (zp[1024 + tid + 384] + zp[1536 + tid + 384]);
            float iv = sigmoidf_(z0);            // gate order i, f, g, o
            float fv = sigmoidf_(z1);
            float gv = fmaxf(z2, 0.0f);          // candidate: relu
            float ov = sigmoidf_(z3);
            cst = fv * cst + iv * gv;            // c = f*c + i*g
            hs[tid] = ov * fmaxf(cst, 0.0f);     // h = o*relu(c)
            zc0 = zn0; zc1 = zn1; zc2 = zn2; zc3 = zn3;
        }
        __syncthreads();   // barrier 2: hs(t+1) visible to all
    }

    if (upd) {
        float h = hs[tid];
        cbuf[(size_t)row * H2 + tid] = cst;
        hbuf[(size_t)row * H2 + tid] = h;
        if (LAST) h2out[(size_t)row * H2 + tid] = h;
    }
}

// =================== dense + softmax ===================
__global__ __launch_bounds__(64, 1)
void dense_softmax_kernel(const float* __restrict__ h2, const float* __restrict__ Wd,
                          const float* __restrict__ bd, float* __restrict__ out)
{
    const int b = blockIdx.x;
    const int k = threadIdx.x;
    __shared__ __align__(16) float hsm[H2];
    if (k < H2 / 4) ((f4v*)hsm)[k] = ((const f4v*)(h2 + (size_t)b * H2))[k];
    __syncthreads();

    float logit = -1e30f;
    if (k < NCLS) {
        float acc = bd[k];
#pragma unroll
        for (int d = 0; d < H2; ++d) acc += hsm[d] * Wd[d * NCLS + k];
        logit = acc;
    }
    float m = logit;
#pragma unroll
    for (int off = 32; off >= 1; off >>= 1) m = fmaxf(m, __shfl_xor(m, off, 64));
    float e = (k < NCLS) ? __expf(logit - m) : 0.0f;
    float s = e;
#pragma unroll
    for (int off = 32; off >= 1; off >>= 1) s += __shfl_xor(s, off, 64);
    if (k < NCLS) out[(size_t)b * NCLS + k] = e / s;
}

// =================== fallback (round-1) kernels ===================
__global__ __launch_bounds__(448, 1)
void lstm1_fb(const float* __restrict__ x, const float* __restrict__ W1,
              const float* __restrict__ U1, const float* __restrict__ b1,
              float* __restrict__ h1out)
{
    const int b = blockIdx.x;
    const int k = threadIdx.x;
    __shared__ __align__(16) float xs[IN_DIM];
    __shared__ __align__(16) float hs[H1];
    __shared__ __align__(16) float zs[4 * H1];
    float w1r[IN_DIM];
    float u1r[H1];
    float bias = 0.0f;
    if (k < 4 * H1) {
        bias = b1[k];
#pragma unroll
        for (int d = 0; d < IN_DIM; ++d) w1r[d] = W1[d * (4 * H1) + k];
#pragma unroll
        for (int j = 0; j < H1; ++j) u1r[j] = U1[j * (4 * H1) + k];
    }
    if (k < H1) hs[k] = 0.0f;
    if (k < IN_DIM / 4)
        ((float4*)xs)[k] = ((const float4*)(x + ((size_t)b * T_SEQ) * IN_DIM))[k];
    float c = 0.0f;
    __syncthreads();
    for (int t = 0; t < T_SEQ; ++t) {
        if (k < 4 * H1) {
            float acc0 = bias, acc1 = 0.f, acc2 = 0.f, acc3 = 0.f;
#pragma unroll
            for (int q = 0; q < IN_DIM / 4; ++q) {
                float4 xv = ((const float4*)xs)[q];
                acc0 += xv.x * w1r[4 * q]; acc1 += xv.y * w1r[4 * q + 1];
                acc2 += xv.z * w1r[4 * q + 2]; acc3 += xv.w * w1r[4 * q + 3];
            }
#pragma unroll
            for (int q = 0; q < H1 / 4; ++q) {
                float4 hv = ((const float4*)hs)[q];
                acc0 += hv.x * u1r[4 * q]; acc1 += hv.y * u1r[4 * q + 1];
                acc2 += hv.z * u1r[4 * q + 2]; acc3 += hv.w * u1r[4 * q + 3];
            }
            float zv = (acc0 + acc1) + (acc2 + acc3);
            zs[k] = (k >= 2 * H1 && k < 3 * H1) ? fmaxf(zv, 0.0f) : sigmoidf_(zv);
        }
        __syncthreads();
        if (k < H1) {
            float i = zs[k], f = zs[k + H1], g = zs[k + 2 * H1], o = zs[k + 3 * H1];
            c = f * c + i * g;
            float h = o * fmaxf(c, 0.0f);
            hs[k] = h;
            h1out[((size_t)t * BATCH + b) * H1 + k] = h;
        }
        int tn = t + 1;
        if (tn < T_SEQ && k < IN_DIM / 4)
            ((float4*)xs)[k] = ((const float4*)(x + ((size_t)b * T_SEQ + tn) * IN_DIM))[k];
        __syncthreads();
    }
}

__global__ __launch_bounds__(512, 1)
void lstm2_fb(const float* __restrict__ h1in, const float* __restrict__ W2,
              const float* __restrict__ U2, const float* __restrict__ b2,
              float* __restrict__ h2out)
{
    const int b = blockIdx.x;
    const int k = threadIdx.x;
    __shared__ __align__(16) float ps[H1];
    __shared__ __align__(16) float hs[H2];
    __shared__ __align__(16) float zs[4 * H2];
    float w2r[H1];
    float u2r[H2];
    float bias = b2[k];
#pragma unroll
    for (int j = 0; j < H1; ++j) w2r[j] = W2[j * (4 * H2) + k];
#pragma unroll
    for (int j = 0; j < H2; ++j) u2r[j] = U2[j * (4 * H2) + k];
    if (k < H2) hs[k] = 0.0f;
    if (k < H1 / 4)
        ((float4*)ps)[k] = ((const float4*)(h1in + (size_t)b * H1))[k];
    float c = 0.0f;
    float hlast = 0.0f;
    __syncthreads();
    for (int t = 0; t < T_SEQ; ++t) {
        float acc0 = bias, acc1 = 0.f, acc2 = 0.f, acc3 = 0.f;
#pragma unroll
        for (int q = 0; q < H1 / 4; ++q) {
            float4 pv = ((const float4*)ps)[q];
            acc0 += pv.x * w2r[4 * q]; acc1 += pv.y * w2r[4 * q + 1];
            acc2 += pv.z * w2r[4 * q + 2]; acc3 += pv.w * w2r[4 * q + 3];
        }
#pragma unroll
        for (int q = 0; q < H2 / 4; ++q) {
            float4 hv = ((const float4*)hs)[q];
            acc0 += hv.x * u2r[4 * q]; acc1 += hv.y * u2r[4 * q + 1];
            acc2 += hv.z * u2r[4 * q + 2]; acc3 += hv.w * u2r[4 * q + 3];
        }
        float zv = (acc0 + acc1) + (acc2 + acc3);
        zs[k] = (k >= 2 * H2 && k < 3 * H2) ? fmaxf(zv, 0.0f) : sigmoidf_(zv);
        __syncthreads();
        if (k < H2) {
            float i = zs[k], f = zs[k + H2], g = zs[k + 2 * H2], o = zs[k + 3 * H2];
            c = f * c + i * g;
            hlast = o * fmaxf(c, 0.0f);
            hs[k] = hlast;
        }
        int tn = t + 1;
        if (tn < T_SEQ && k < H1 / 4)
            ((float4*)ps)[k] = ((const float4*)(h1in + ((size_t)tn * BATCH + b) * H1))[k];
        __syncthreads();
    }
    if (k < H2) h2out[(size_t)b * H2 + k] = hlast;
}

extern "C" void kernel_launch(void* const* d_in, const int* in_sizes, int n_in,
                              void* d_out, int out_size, void* d_ws, size_t ws_size,
                              hipStream_t stream) {
    const float* x  = (const float*)d_in[0];
    const float* W1 = (const float*)d_in[1];
    const float* U1 = (const float*)d_in[2];
    const float* b1 = (const float*)d_in[3];
    const float* W2 = (const float*)d_in[4];
    const float* U2 = (const float*)d_in[5];
    const float* b2 = (const float*)d_in[6];
    const float* Wd = (const float*)d_in[7];
    const float* bd = (const float*)d_in[8];
    float* out = (float*)d_out;

    const size_t zx_elems = (size_t)T_SEQ * BATCH * 400;   // 52428800
    const size_t h1_elems = (size_t)T_SEQ * BATCH * H1;    // 13107200
    const size_t st_elems = (size_t)BATCH * H2;            // 65536
    const size_t need = (zx_elems + h1_elems + 3 * st_elems) * sizeof(float);  // 262.93 MB

    if (ws_size >= need) {
        float* zxbuf = (float*)d_ws;
        float* h1buf = zxbuf + zx_elems;
        float* cbuf  = h1buf + h1_elems;
        float* hbuf  = cbuf + st_elems;
        float* h2buf = hbuf + st_elems;
        const int TC = T_SEQ / 2;   // 128-step chunks

        // zx1 = x @ W1 + b1 -> [T][B][400]
        hipLaunchKernelGGL((proj_kernel<IN_DIM, 4 * H1, true>), dim3(1024, 4), dim3(256), 0, stream,
                           x, W1, b1, zxbuf);
        hipLaunchKernelGGL(rec1_kernel, dim3(BATCH), dim3(512), 0, stream,
                           zxbuf, U1, h1buf);
        // ---- layer 2, chunk A (t = 0..127): zx2 chunk overwrites zx1 region ----
        hipLaunchKernelGGL((proj_kernel<H1, 4 * H2, false>), dim3(512, 4), dim3(256), 0, stream,
                           h1buf, W2, b2, zxbuf);
        hipLaunchKernelGGL((rec2_chunk<true, false>), dim3(BATCH), dim3(512), 0, stream,
                           zxbuf, U2, cbuf, hbuf, h2buf, TC);
        // ---- layer 2, chunk B (t = 128..255) ----
        hipLaunchKernelGGL((proj_kernel<H1, 4 * H2, false>), dim3(512, 4), dim3(256), 0, stream,
                           h1buf + (size_t)TC * BATCH * H1, W2, b2, zxbuf);
        hipLaunchKernelGGL((rec2_chunk<false, true>), dim3(BATCH), dim3(512), 0, stream,
                           zxbuf, U2, cbuf, hbuf, h2buf, TC);

        hipLaunchKernelGGL(dense_softmax_kernel, dim3(BATCH), dim3(64), 0, stream,
                           h2buf, Wd, bd, out);
    } else {
        // fallback: round-1 fused kernels (needs ~52.7 MB)
        float* h1buf = (float*)d_ws;
        float* h2buf = h1buf + h1_elems;
        hipLaunchKernelGGL(lstm1_fb, dim3(BATCH), dim3(448), 0, stream, x, W1, U1, b1, h1buf);
        hipLaunchKernelGGL(lstm2_fb, dim3(BATCH), dim3(512), 0, stream, h1buf, W2, U2, b2, h2buf);
        hipLaunchKernelGGL(dense_softmax_kernel, dim3(BATCH), dim3(64), 0, stream, h2buf, Wd, bd, out);
    }
}